// Round 13
// baseline (5858.464 us; speedup 1.0000x reference)
//
#include <hip/hip_runtime.h>
#include <cstdint>
#include <cstddef>

// Decoder (DA-RNN): B=512, T=256, E=D=256.
// Round 15: dependency-graph packing. Gates (the 512KB whh stream) is OFF the
// critical path (consumed only by pointwise) -> split it into two k-segments
// running concurrent with q (phase A) and scores (phase B); partials
// accumulate through LDS gfull (no register crosses a barrier - 6x-confirmed
// constraint). Scores go full-e per thread (tid<512) with in-wave reduce ->
// spart AND the combine phase die: 3 barriers/step (was 4).
// Also: (a) hcH padded [2][520] (c at +264) - kills R14's 1.34e8 bank
// conflicts (khq 512B-apart addrs aliased to one bank group); (b) freed LDS
// -> stage 16 even Ph2 chunk-ids (128KB), stream the 16 odd. LDS ~159KB.

typedef _Float16 half8 __attribute__((ext_vector_type(8)));
typedef _Float16 half4v __attribute__((ext_vector_type(4)));
typedef _Float16 half2v __attribute__((ext_vector_type(2)));

__device__ __forceinline__ float rcpf_(float x) { return __builtin_amdgcn_rcpf(x); }
__device__ __forceinline__ float sigmoidf_(float x) { return rcpf_(1.f + __expf(-x)); }
__device__ __forceinline__ float tanhf_(float x) { return 1.f - 2.f * rcpf_(1.f + __expf(2.f * x)); }

#if defined(__has_builtin)
#if __has_builtin(__builtin_amdgcn_fdot2)
#define HAS_FDOT2 1
#endif
#endif
#ifndef HAS_FDOT2
#define HAS_FDOT2 0
#endif

__device__ __forceinline__ float fdot2_(half2v a, half2v b, float c) {
#if HAS_FDOT2
  return __builtin_amdgcn_fdot2(a, b, c, false);
#else
  return fmaf((float)a[0], (float)b[0], fmaf((float)a[1], (float)b[1], c));
#endif
}

__device__ __forceinline__ float dot8_(half8 w, half8 h, float acc) {
  acc = fdot2_(__builtin_shufflevector(w, w, 0, 1), __builtin_shufflevector(h, h, 0, 1), acc);
  acc = fdot2_(__builtin_shufflevector(w, w, 2, 3), __builtin_shufflevector(h, h, 2, 3), acc);
  acc = fdot2_(__builtin_shufflevector(w, w, 4, 5), __builtin_shufflevector(h, h, 4, 5), acc);
  acc = fdot2_(__builtin_shufflevector(w, w, 6, 7), __builtin_shufflevector(h, h, 6, 7), acc);
  return acc;
}

// ---------------- prep kernels (all unchanged from R14) ----------------

// wT[e*256+f] = attn_w1[f*768 + 512 + e]   (transposed w1_enc, fp32)
__global__ void k_prep_wT(const float* __restrict__ w1, float* __restrict__ wT) {
  int id = blockIdx.x * 256 + threadIdx.x;
  int e = id >> 8, f = id & 255;
  wT[id] = w1[f * 768 + 512 + e];
}

// x -> fp16 (4 elems/thread), layout unchanged [b][t][e]
__global__ void k_prep_xh(const float* __restrict__ x, _Float16* __restrict__ xh) {
  int id = blockIdx.x * 256 + threadIdx.x;
  float4 v = reinterpret_cast<const float4*>(x)[id];
  half4v h;
  h[0] = (_Float16)v.x; h[1] = (_Float16)v.y; h[2] = (_Float16)v.z; h[3] = (_Float16)v.w;
  reinterpret_cast<half4v*>(xh)[id] = h;
}

// w1hcP2[(c*512 + e*2 + kh)*8 + m] = w1[e*768 + kh*256 + c*8 + m], c in [0,32)
// (k_scan q-thread tid = e*2+kh reads chunk c at half8 index c*512 + tid)
__global__ void k_prep_w1hcQ(const float* __restrict__ w1, _Float16* __restrict__ o) {
  int id = blockIdx.x * 256 + threadIdx.x;  // 131072 total
  int m = id & 7, lane = (id >> 3) & 511, c = id >> 12;
  int e = lane >> 1, kh = lane & 1;
  o[id] = (_Float16)w1[e * 768 + kh * 256 + c * 8 + m];
}

// whhJ[(c*1024 + j)*8 + m] = Whh[j*256 + c*8 + m], c in [0,32)
// (gates thread u handles j in {u, u+512}, both lane-consecutive)
__global__ void k_prep_whhG(const float* __restrict__ whh, _Float16* __restrict__ o) {
  int id = blockIdx.x * 256 + threadIdx.x;  // 262144 total
  int m = id & 7, j = (id >> 3) & 1023, c = id >> 13;
  o[id] = (_Float16)whh[j * 256 + c * 8 + m];
}

// xf[b*256+t] = sum_e x[b,t,e] * fcw[e]   (fp32)
__global__ __launch_bounds__(256) void k_xf(const float* __restrict__ x,
                                            const float* __restrict__ fcw,
                                            float* __restrict__ xf) {
  __shared__ float xl[16][256];
  __shared__ float fw[256];
  __shared__ float part[16][17];
  const int tid = threadIdx.x;
  const int m0 = blockIdx.x * 16;
  fw[tid] = fcw[tid];
#pragma unroll
  for (int r = 0; r < 16; ++r) xl[r][tid] = x[(size_t)(m0 + r) * 256 + tid];
  __syncthreads();
  int r = tid >> 4, p = tid & 15;
  float s = 0.f;
#pragma unroll
  for (int u = 0; u < 16; ++u) s = fmaf(xl[r][p * 16 + u], fw[p * 16 + u], s);
  part[r][p] = s;
  __syncthreads();
  if (tid < 16) {
    float t = 0.f;
#pragma unroll
    for (int p2 = 0; p2 < 16; ++p2) t += part[tid][p2];
    xf[m0 + tid] = t;
  }
}

// enc_proj GEMM + bias, store P=exp(2*encp) fp16 in layout [b][e/8][t][e%8]
__global__ __launch_bounds__(256) void k_encp(const float* __restrict__ x,
                                              const float* __restrict__ wT,
                                              const float* __restrict__ b1,
                                              _Float16* __restrict__ Ph2) {
  __shared__ __align__(16) float xl[16][256];
  const int tid = threadIdx.x;
  const int m0 = blockIdx.x * 16;
#pragma unroll
  for (int r = 0; r < 16; ++r) xl[r][tid] = x[(size_t)(m0 + r) * 256 + tid];
  __syncthreads();
  float acc[16];
#pragma unroll
  for (int r = 0; r < 16; ++r) acc[r] = 0.f;
  for (int e = 0; e < 256; e += 4) {
    float w0 = wT[(e + 0) * 256 + tid];
    float w1_ = wT[(e + 1) * 256 + tid];
    float w2_ = wT[(e + 2) * 256 + tid];
    float w3_ = wT[(e + 3) * 256 + tid];
#pragma unroll
    for (int r = 0; r < 16; ++r) {
      float4 xv = *reinterpret_cast<const float4*>(&xl[r][e]);
      acc[r] = fmaf(xv.x, w0, acc[r]);
      acc[r] = fmaf(xv.y, w1_, acc[r]);
      acc[r] = fmaf(xv.z, w2_, acc[r]);
      acc[r] = fmaf(xv.w, w3_, acc[r]);
    }
  }
  float bb = b1[tid];
  const int e = tid;
#pragma unroll
  for (int r = 0; r < 16; ++r) {
    int m = m0 + r, b = m >> 8, t = m & 255;
    float p = __expf(2.f * (acc[r] + bb));
    Ph2[((size_t)(b * 32 + (e >> 3)) * 256 + t) * 8 + (e & 7)] = (_Float16)p;
  }
}

#define SC1(pv, c) { \
  float4 qa = q4[2*(c)], wa = w4[2*(c)]; \
  sacc0 = fmaf(wa.x, rcpf_(fmaf((float)pv[0], qa.x, 1.f)), sacc0); \
  sacc1 = fmaf(wa.y, rcpf_(fmaf((float)pv[1], qa.y, 1.f)), sacc1); \
  sacc0 = fmaf(wa.z, rcpf_(fmaf((float)pv[2], qa.z, 1.f)), sacc0); \
  sacc1 = fmaf(wa.w, rcpf_(fmaf((float)pv[3], qa.w, 1.f)), sacc1); \
  float4 qb = q4[2*(c)+1], wb = w4[2*(c)+1]; \
  sacc0 = fmaf(wb.x, rcpf_(fmaf((float)pv[4], qb.x, 1.f)), sacc0); \
  sacc1 = fmaf(wb.y, rcpf_(fmaf((float)pv[5], qb.y, 1.f)), sacc1); \
  sacc0 = fmaf(wb.z, rcpf_(fmaf((float)pv[6], qb.z, 1.f)), sacc0); \
  sacc1 = fmaf(wb.w, rcpf_(fmaf((float)pv[7], qb.w, 1.f)), sacc1); }

// ---------------- the scan ----------------
// grid 256 x 1024 threads; wg owns 2 batch rows; 256 steps; 3 barriers/step.
__global__ __launch_bounds__(1024, 4) void k_scan(
    const _Float16* __restrict__ Ph2, const _Float16* __restrict__ xh,
    const _Float16* __restrict__ w1hcQ, const _Float16* __restrict__ whhG,
    const float* __restrict__ xf, const float* __restrict__ y_hist,
    const float* __restrict__ w2g, const float* __restrict__ Wih,
    const float* __restrict__ bih, const float* __restrict__ bhh,
    const float* __restrict__ fcw, const float* __restrict__ fcb,
    const float* __restrict__ fcfw, const float* __restrict__ fcfb,
    float* __restrict__ out) {
  __shared__ __align__(16) float hc[2][512];        // fp32 [g][ h | c ]
  __shared__ __align__(16) _Float16 hcH[2][520];    // fp16 mirror; h at 0..255, c at 264..519 (pad kills khq bank alias)
  __shared__ __align__(16) float Qs[2][256];        // exp(2q)
  __shared__ __align__(16) float ealpha[2][256];
  __shared__ __align__(16) float gfull[2][1024];    // gate GEMV accumulators (seg1 write, seg2 +=)
  __shared__ __align__(16) _Float16 PhL[2][16][256][8]; // 128KB: even Ph2 chunk-ids staged once; epilogue cpart alias
  __shared__ __align__(16) float w2l[256];
  __shared__ __align__(16) float Wihl[1024];
  __shared__ __align__(16) float bl[1024];
  __shared__ __align__(16) float xfL[2][256];
  __shared__ __align__(16) float yhL[2][256];
  __shared__ float redA[8], redB[8];

  const int tid = threadIdx.x;
  const int b0 = blockIdx.x * 2;
  const int lo = tid & 255;
  const int wv = tid >> 6, lane = tid & 63;

  // ---- init + one-time Ph2 stage (16 even chunk-ids x 2 rows = 128KB) ----
  ((float*)hc)[tid] = 0.f;
  if (tid < 520) {
    hcH[0][tid] = (_Float16)0.f;
    hcH[1][tid] = (_Float16)0.f;
  }
  if (tid < 256) w2l[tid] = w2g[tid];
  Wihl[tid & 1023] = Wih[tid & 1023];
  bl[tid] = bih[tid] + bhh[tid];
  if (tid < 512) {
    int gi = tid >> 8, ti = tid & 255;
    xfL[gi][ti] = xf[(size_t)(b0 + gi) * 256 + ti];
    yhL[gi][ti] = y_hist[(size_t)(b0 + gi) * 256 + ti];
  }
  {
    half8* phl8 = reinterpret_cast<half8*>(&PhL[0][0][0][0]);
    const half8* ph8 = reinterpret_cast<const half8*>(Ph2);
#pragma unroll
    for (int u2 = 0; u2 < 8; ++u2) {
      int slot = u2 * 1024 + tid;         // 0..8191
      int g = slot >= 4096;
      int rem = slot - g * 4096;
      int ci = rem >> 8;                  // 0..15
      int t = rem & 255;
      int cc = 2 * ci;                    // staged chunk ids: all even
      phl8[slot] = ph8[((size_t)(b0 + g) * 32 + cc) * 256 + t];
    }
  }
  __syncthreads();
  float w2sum = 0.f;
  for (int e2 = 0; e2 < 256; ++e2) w2sum += w2l[e2];
  const float fcb0 = fcb[0];
  const float fcwy = fcw[256];

  // per-thread role constants
  // A/q (tid<512): e = tid>>1, khq = tid&1 (lane-pair k-split), both rows
  const half8* wq2 = reinterpret_cast<const half8*>(w1hcQ) + tid;  // chunk c: wq2[c*512]
  const int khq = tid & 1;
  // A,B/gates (tid>=512): ug = tid-512; j in {ug, ug+512}, k seg1 c=0..15, seg2 c=16..31
  const int ug = (tid - 512) & 511;
  const half8* wgJ = reinterpret_cast<const half8*>(whhG) + ug;    // j0: [c*1024], j1: [c*1024+512]
  // B/scores (tid<512): gs = (tid>>8)&1, t = lo, FULL e-range
  const int gs = (tid >> 8) & 1;
  const half8* prow = reinterpret_cast<const half8*>(Ph2) +
                      ((size_t)((b0 + gs) * 32)) * 256 + lo;
  const half8* phlR = reinterpret_cast<const half8*>(&PhL[0][0][0][0]) +
                      (gs * 16) * 256 + lo;
  // D/pointwise (tid<512): gp
  const int gp = (tid >> 8) & 1;

#pragma unroll 1
  for (int s = 0; s < 256; ++s) {
    // ---- phase A: q (lane-pair, both rows) || gates seg1 (c=0..15) ----
    if (tid < 512) {
      float a0 = 0.f, a1 = 0.f;
      const half8* hp0 = reinterpret_cast<const half8*>(&hcH[0][khq * 264]);
      const half8* hp1 = reinterpret_cast<const half8*>(&hcH[1][khq * 264]);
#pragma unroll 8
      for (int c = 0; c < 32; ++c) {
        half8 w = wq2[c * 512];
        a0 = dot8_(w, hp0[c], a0);   // pad -> khq=0/1 hit disjoint bank groups
        a1 = dot8_(w, hp1[c], a1);
      }
      a0 += __shfl_xor(a0, 1);       // lane-pair combine: q complete
      a1 += __shfl_xor(a1, 1);
      if (khq == 0) {
        int e = tid >> 1;
        Qs[0][e] = __expf(2.f * a0);
        Qs[1][e] = __expf(2.f * a1);
      }
    } else {
      float ac00 = 0.f, ac01 = 0.f, ac10 = 0.f, ac11 = 0.f;  // [jslot][row]
      const half8* hg0 = reinterpret_cast<const half8*>(&hcH[0][0]);
      const half8* hg1 = reinterpret_cast<const half8*>(&hcH[1][0]);
#pragma unroll 4
      for (int c = 0; c < 16; ++c) {
        half8 h0 = hg0[c];   // broadcast
        half8 h1 = hg1[c];
        half8 w0 = wgJ[c * 1024];
        half8 w1v = wgJ[c * 1024 + 512];
        ac00 = dot8_(w0, h0, ac00);  ac01 = dot8_(w0, h1, ac01);
        ac10 = dot8_(w1v, h0, ac10); ac11 = dot8_(w1v, h1, ac11);
      }
      gfull[0][ug] = ac00;
      gfull[1][ug] = ac01;
      gfull[0][ug + 512] = ac10;
      gfull[1][ug + 512] = ac11;
    }
    __syncthreads();  // B1

    // ---- phase B: scores full-e + in-wave reduce (tid<512) || gates seg2 (c=16..31) ----
    if (tid < 512) {
      float sacc0 = 0.f, sacc1 = 0.f;
      {
        const float4* q4 = reinterpret_cast<const float4*>(&Qs[gs][0]);
        const float4* w4 = reinterpret_cast<const float4*>(&w2l[0]);
        // 16 streamed odd chunks: issue all first (latency hides under LDS math)
        half8 p1_ = prow[1 * 256];   half8 p3_ = prow[3 * 256];
        half8 p5_ = prow[5 * 256];   half8 p7_ = prow[7 * 256];
        half8 p9_ = prow[9 * 256];   half8 p11_ = prow[11 * 256];
        half8 p13_ = prow[13 * 256]; half8 p15_ = prow[15 * 256];
        half8 p17_ = prow[17 * 256]; half8 p19_ = prow[19 * 256];
        half8 p21_ = prow[21 * 256]; half8 p23_ = prow[23 * 256];
        half8 p25_ = prow[25 * 256]; half8 p27_ = prow[27 * 256];
        half8 p29_ = prow[29 * 256]; half8 p31_ = prow[31 * 256];
        // 16 staged even chunks from LDS (zero latency)
        { half8 l = phlR[0 * 256];   SC1(l, 0) }
        { half8 l = phlR[1 * 256];   SC1(l, 2) }
        { half8 l = phlR[2 * 256];   SC1(l, 4) }
        { half8 l = phlR[3 * 256];   SC1(l, 6) }
        { half8 l = phlR[4 * 256];   SC1(l, 8) }
        { half8 l = phlR[5 * 256];   SC1(l, 10) }
        { half8 l = phlR[6 * 256];   SC1(l, 12) }
        { half8 l = phlR[7 * 256];   SC1(l, 14) }
        { half8 l = phlR[8 * 256];   SC1(l, 16) }
        { half8 l = phlR[9 * 256];   SC1(l, 18) }
        { half8 l = phlR[10 * 256];  SC1(l, 20) }
        { half8 l = phlR[11 * 256];  SC1(l, 22) }
        { half8 l = phlR[12 * 256];  SC1(l, 24) }
        { half8 l = phlR[13 * 256];  SC1(l, 26) }
        { half8 l = phlR[14 * 256];  SC1(l, 28) }
        { half8 l = phlR[15 * 256];  SC1(l, 30) }
        // streamed odd chunks
        SC1(p1_, 1)   SC1(p3_, 3)   SC1(p5_, 5)   SC1(p7_, 7)
        SC1(p9_, 9)   SC1(p11_, 11) SC1(p13_, 13) SC1(p15_, 15)
        SC1(p17_, 17) SC1(p19_, 19) SC1(p21_, 21) SC1(p23_, 23)
        SC1(p25_, 25) SC1(p27_, 27) SC1(p29_, 29) SC1(p31_, 31)
      }
      float sc = w2sum - 2.f * (sacc0 + sacc1);
      float ea = __expf(sc);  // no max-sub: |sc| <= ~21, fp32-safe
      ealpha[gs][lo] = ea;
      float ef = ea * xfL[gs][lo];
      float es = ea;
#pragma unroll
      for (int off = 32; off > 0; off >>= 1) {
        es += __shfl_xor(es, off);
        ef += __shfl_xor(ef, off);
      }
      if (lane == 0) { redA[wv] = es; redB[wv] = ef; }
    } else {
      float ac00 = 0.f, ac01 = 0.f, ac10 = 0.f, ac11 = 0.f;
      const half8* hg0 = reinterpret_cast<const half8*>(&hcH[0][0]);
      const half8* hg1 = reinterpret_cast<const half8*>(&hcH[1][0]);
#pragma unroll 4
      for (int c = 16; c < 32; ++c) {
        half8 h0 = hg0[c];
        half8 h1 = hg1[c];
        half8 w0 = wgJ[c * 1024];
        half8 w1v = wgJ[c * 1024 + 512];
        ac00 = dot8_(w0, h0, ac00);  ac01 = dot8_(w0, h1, ac01);
        ac10 = dot8_(w1v, h0, ac10); ac11 = dot8_(w1v, h1, ac11);
      }
      gfull[0][ug] += ac00;
      gfull[1][ug] += ac01;
      gfull[0][ug + 512] += ac10;
      gfull[1][ug + 512] += ac11;
    }
    __syncthreads();  // B2

    // ---- phase D: LSTM pointwise (tid < 512) ----
    if (tid < 512) {
      float es = (gp == 0) ? (redA[0] + redA[1] + redA[2] + redA[3])
                           : (redA[4] + redA[5] + redA[6] + redA[7]);
      float ef = (gp == 0) ? (redB[0] + redB[1] + redB[2] + redB[3])
                           : (redB[4] + redB[5] + redB[6] + redB[7]);
      float yt = ef * rcpf_(es) + fmaf(yhL[gp][s], fcwy, fcb0);
      float gi = fmaf(yt, Wihl[lo], bl[lo]) + gfull[gp][lo];
      float gf = fmaf(yt, Wihl[256 + lo], bl[256 + lo]) + gfull[gp][256 + lo];
      float gc = fmaf(yt, Wihl[512 + lo], bl[512 + lo]) + gfull[gp][512 + lo];
      float go = fmaf(yt, Wihl[768 + lo], bl[768 + lo]) + gfull[gp][768 + lo];
      float iv = sigmoidf_(gi), fv = sigmoidf_(gf), gv = tanhf_(gc), ov = sigmoidf_(go);
      float cold = hc[gp][256 + lo];
      float cn = fmaf(fv, cold, iv * gv);
      float hn = ov * tanhf_(cn);
      hc[gp][lo] = hn;
      hc[gp][256 + lo] = cn;
      hcH[gp][lo] = (_Float16)hn;
      hcH[gp][264 + lo] = (_Float16)cn;
    }
    __syncthreads();  // B3
  }

  // ---- epilogue: context from step-255 ealpha, then out = [h|ctx].fcf ----
  // read last-step softmax sums BEFORE redA/redB get reused
  const float rsA = rcpf_(redA[0] + redA[1] + redA[2] + redA[3]);
  const float rsB = rcpf_(redA[4] + redA[5] + redA[6] + redA[7]);

  float* cpartF = reinterpret_cast<float*>(&PhL[0][0][0][0]);  // 32KB alias in 128KB stage
  {
    const int gc = tid >> 9, t16 = (tid >> 5) & 15, l5 = tid & 31;
    const half8* xrow = reinterpret_cast<const half8*>(xh) +
                        ((size_t)(b0 + gc) * 256 + t16 * 16) * 32 + l5;
    float acx[8];
#pragma unroll
    for (int m = 0; m < 8; ++m) acx[m] = 0.f;
#pragma unroll 4
    for (int it = 0; it < 16; ++it) {
      float al = ealpha[gc][t16 * 16 + it];
      half8 xv = xrow[it * 32];
#pragma unroll
      for (int m = 0; m < 8; ++m) acx[m] = fmaf(al, (float)xv[m], acx[m]);
    }
    float* dst = &cpartF[((gc * 16 + t16) * 256) + l5 * 8];
    *reinterpret_cast<float4*>(dst) = *reinterpret_cast<float4*>(&acx[0]);
    *reinterpret_cast<float4*>(dst + 4) = *reinterpret_cast<float4*>(&acx[4]);
  }
  __syncthreads();

  if (tid < 512) {
    float cv = 0.f;
#pragma unroll
    for (int u = 0; u < 16; ++u) cv += cpartF[((gp * 16 + u) * 256) + lo];
    cv *= (gp == 0) ? rsA : rsB;
    float hval = hc[gp][lo];
    float p0 = hval * fcfw[lo] + cv * fcfw[256 + lo];
    float p1 = hval * fcfw[512 + lo] + cv * fcfw[768 + lo];
#pragma unroll
    for (int off = 32; off > 0; off >>= 1) {
      p0 += __shfl_xor(p0, off);
      p1 += __shfl_xor(p1, off);
    }
    if (lane == 0) { redA[wv] = p0; redB[wv] = p1; }
  }
  __syncthreads();
  if (tid < 4) {
    int g2 = tid >> 1, o = tid & 1;
    const float* r = (o == 0) ? redA : redB;
    float v = fcfb[o] + r[g2 * 4 + 0] + r[g2 * 4 + 1] + r[g2 * 4 + 2] + r[g2 * 4 + 3];
    out[(b0 + g2) * 2 + o] = v;
  }
}

extern "C" void kernel_launch(void* const* d_in, const int* in_sizes, int n_in,
                              void* d_out, int out_size, void* d_ws, size_t ws_size,
                              hipStream_t stream) {
  (void)in_sizes; (void)n_in; (void)out_size; (void)ws_size;
  const float* x    = (const float*)d_in[0];
  const float* yh   = (const float*)d_in[1];
  const float* w1   = (const float*)d_in[2];
  const float* b1   = (const float*)d_in[3];
  const float* w2   = (const float*)d_in[4];
  /* d_in[5] attn_b2: softmax-invariant, unused */
  const float* Wih  = (const float*)d_in[6];
  const float* Whh  = (const float*)d_in[7];
  const float* bih  = (const float*)d_in[8];
  const float* bhh  = (const float*)d_in[9];
  const float* fcw  = (const float*)d_in[10];
  const float* fcb  = (const float*)d_in[11];
  const float* fcfw = (const float*)d_in[12];
  const float* fcfb = (const float*)d_in[13];
  float* out = (float*)d_out;

  char* ws = (char*)d_ws;
  _Float16* Ph2   = (_Float16*)(ws);                      // 67108864 B
  _Float16* xh    = (_Float16*)(ws + (size_t)67108864);   // 67108864 B
  float*    wT    = (float*)   (ws + (size_t)134217728);  // 262144 B
  _Float16* w1hcQ = (_Float16*)(ws + (size_t)134479872);  // 262144 B
  _Float16* whhG  = (_Float16*)(ws + (size_t)134742016);  // 524288 B
  float*    xf    = (float*)   (ws + (size_t)135266304);  // 524288 B
  // total: 135790592 B (~129.5 MB)

  k_prep_wT   <<<256,   256, 0, stream>>>(w1, wT);
  k_prep_xh   <<<32768, 256, 0, stream>>>(x, xh);
  k_prep_w1hcQ<<<512,   256, 0, stream>>>(w1, w1hcQ);
  k_prep_whhG <<<1024,  256, 0, stream>>>(Whh, whhG);
  k_xf        <<<8192,  256, 0, stream>>>(x, fcw, xf);
  k_encp      <<<8192,  256, 0, stream>>>(x, wT, b1, Ph2);
  k_scan      <<<256,  1024, 0, stream>>>(Ph2, xh, w1hcQ, whhG, xf, yh, w2, Wih,
                                          bih, bhh, fcw, fcb, fcfw, fcfb, out);
}

// Round 14
// 3661.504 us; speedup vs baseline: 1.6000x; 1.6000x over previous
//
#include <hip/hip_runtime.h>
#include <cstdint>
#include <cstddef>

// Decoder (DA-RNN): B=512, T=256, E=D=256.
// Round 16: REVERT to R14/R12 structure (verified best: 3590us k_scan, L2-
// resident, FETCH 86MB) + ONE fix: hcH padded [2][520] with c-state at half-
// offset 264 (528B = bank 4 mod 32). R14's lane-pair q-split read khq=0/1
// addresses 512B apart = SAME 4-bank group -> 1.34e8 conflict cycles (~6%).
// Pad makes the pair hit disjoint bank groups. Nothing else changes.
// (R15's concurrent whh+Ph2 streams in one phase destroyed L2/L3 residency:
// FETCH 86MB->4.6GB, dur +54%. Phase layout is load-bearing for caching.)

typedef _Float16 half8 __attribute__((ext_vector_type(8)));
typedef _Float16 half4v __attribute__((ext_vector_type(4)));
typedef _Float16 half2v __attribute__((ext_vector_type(2)));

__device__ __forceinline__ float rcpf_(float x) { return __builtin_amdgcn_rcpf(x); }
__device__ __forceinline__ float sigmoidf_(float x) { return rcpf_(1.f + __expf(-x)); }
__device__ __forceinline__ float tanhf_(float x) { return 1.f - 2.f * rcpf_(1.f + __expf(2.f * x)); }

#if defined(__has_builtin)
#if __has_builtin(__builtin_amdgcn_fdot2)
#define HAS_FDOT2 1
#endif
#endif
#ifndef HAS_FDOT2
#define HAS_FDOT2 0
#endif

__device__ __forceinline__ float fdot2_(half2v a, half2v b, float c) {
#if HAS_FDOT2
  return __builtin_amdgcn_fdot2(a, b, c, false);
#else
  return fmaf((float)a[0], (float)b[0], fmaf((float)a[1], (float)b[1], c));
#endif
}

__device__ __forceinline__ float dot8_(half8 w, half8 h, float acc) {
  acc = fdot2_(__builtin_shufflevector(w, w, 0, 1), __builtin_shufflevector(h, h, 0, 1), acc);
  acc = fdot2_(__builtin_shufflevector(w, w, 2, 3), __builtin_shufflevector(h, h, 2, 3), acc);
  acc = fdot2_(__builtin_shufflevector(w, w, 4, 5), __builtin_shufflevector(h, h, 4, 5), acc);
  acc = fdot2_(__builtin_shufflevector(w, w, 6, 7), __builtin_shufflevector(h, h, 6, 7), acc);
  return acc;
}

// ---------------- prep kernels ----------------

// wT[e*256+f] = attn_w1[f*768 + 512 + e]   (transposed w1_enc, fp32)
__global__ void k_prep_wT(const float* __restrict__ w1, float* __restrict__ wT) {
  int id = blockIdx.x * 256 + threadIdx.x;
  int e = id >> 8, f = id & 255;
  wT[id] = w1[f * 768 + 512 + e];
}

// x -> fp16 (4 elems/thread), layout unchanged [b][t][e]
__global__ void k_prep_xh(const float* __restrict__ x, _Float16* __restrict__ xh) {
  int id = blockIdx.x * 256 + threadIdx.x;
  float4 v = reinterpret_cast<const float4*>(x)[id];
  half4v h;
  h[0] = (_Float16)v.x; h[1] = (_Float16)v.y; h[2] = (_Float16)v.z; h[3] = (_Float16)v.w;
  reinterpret_cast<half4v*>(xh)[id] = h;
}

// w1hcP2[(c*512 + e*2 + kh)*8 + m] = w1[e*768 + kh*256 + c*8 + m], c in [0,32)
// (k_scan q-thread tid = e*2+kh reads chunk c at half8 index c*512 + tid)
__global__ void k_prep_w1hcQ(const float* __restrict__ w1, _Float16* __restrict__ o) {
  int id = blockIdx.x * 256 + threadIdx.x;  // 131072 total
  int m = id & 7, lane = (id >> 3) & 511, c = id >> 12;
  int e = lane >> 1, kh = lane & 1;
  o[id] = (_Float16)w1[e * 768 + kh * 256 + c * 8 + m];
}

// whhJ[(c*1024 + j)*8 + m] = Whh[j*256 + c*8 + m], c in [0,32)
// (gates thread u handles j in {u, u+512}, both lane-consecutive)
__global__ void k_prep_whhG(const float* __restrict__ whh, _Float16* __restrict__ o) {
  int id = blockIdx.x * 256 + threadIdx.x;  // 262144 total
  int m = id & 7, j = (id >> 3) & 1023, c = id >> 13;
  o[id] = (_Float16)whh[j * 256 + c * 8 + m];
}

// xf[b*256+t] = sum_e x[b,t,e] * fcw[e]   (fp32)
__global__ __launch_bounds__(256) void k_xf(const float* __restrict__ x,
                                            const float* __restrict__ fcw,
                                            float* __restrict__ xf) {
  __shared__ float xl[16][256];
  __shared__ float fw[256];
  __shared__ float part[16][17];
  const int tid = threadIdx.x;
  const int m0 = blockIdx.x * 16;
  fw[tid] = fcw[tid];
#pragma unroll
  for (int r = 0; r < 16; ++r) xl[r][tid] = x[(size_t)(m0 + r) * 256 + tid];
  __syncthreads();
  int r = tid >> 4, p = tid & 15;
  float s = 0.f;
#pragma unroll
  for (int u = 0; u < 16; ++u) s = fmaf(xl[r][p * 16 + u], fw[p * 16 + u], s);
  part[r][p] = s;
  __syncthreads();
  if (tid < 16) {
    float t = 0.f;
#pragma unroll
    for (int p2 = 0; p2 < 16; ++p2) t += part[tid][p2];
    xf[m0 + tid] = t;
  }
}

// enc_proj GEMM + bias, store P=exp(2*encp) fp16 in layout [b][e/8][t][e%8]
__global__ __launch_bounds__(256) void k_encp(const float* __restrict__ x,
                                              const float* __restrict__ wT,
                                              const float* __restrict__ b1,
                                              _Float16* __restrict__ Ph2) {
  __shared__ __align__(16) float xl[16][256];
  const int tid = threadIdx.x;
  const int m0 = blockIdx.x * 16;
#pragma unroll
  for (int r = 0; r < 16; ++r) xl[r][tid] = x[(size_t)(m0 + r) * 256 + tid];
  __syncthreads();
  float acc[16];
#pragma unroll
  for (int r = 0; r < 16; ++r) acc[r] = 0.f;
  for (int e = 0; e < 256; e += 4) {
    float w0 = wT[(e + 0) * 256 + tid];
    float w1_ = wT[(e + 1) * 256 + tid];
    float w2_ = wT[(e + 2) * 256 + tid];
    float w3_ = wT[(e + 3) * 256 + tid];
#pragma unroll
    for (int r = 0; r < 16; ++r) {
      float4 xv = *reinterpret_cast<const float4*>(&xl[r][e]);
      acc[r] = fmaf(xv.x, w0, acc[r]);
      acc[r] = fmaf(xv.y, w1_, acc[r]);
      acc[r] = fmaf(xv.z, w2_, acc[r]);
      acc[r] = fmaf(xv.w, w3_, acc[r]);
    }
  }
  float bb = b1[tid];
  const int e = tid;
#pragma unroll
  for (int r = 0; r < 16; ++r) {
    int m = m0 + r, b = m >> 8, t = m & 255;
    float p = __expf(2.f * (acc[r] + bb));
    Ph2[((size_t)(b * 32 + (e >> 3)) * 256 + t) * 8 + (e & 7)] = (_Float16)p;
  }
}

#define SC1(pv, c) { \
  float4 qa = q4[2*(c)], wa = w4[2*(c)]; \
  sacc0 = fmaf(wa.x, rcpf_(fmaf((float)pv[0], qa.x, 1.f)), sacc0); \
  sacc1 = fmaf(wa.y, rcpf_(fmaf((float)pv[1], qa.y, 1.f)), sacc1); \
  sacc0 = fmaf(wa.z, rcpf_(fmaf((float)pv[2], qa.z, 1.f)), sacc0); \
  sacc1 = fmaf(wa.w, rcpf_(fmaf((float)pv[3], qa.w, 1.f)), sacc1); \
  float4 qb = q4[2*(c)+1], wb = w4[2*(c)+1]; \
  sacc0 = fmaf(wb.x, rcpf_(fmaf((float)pv[4], qb.x, 1.f)), sacc0); \
  sacc1 = fmaf(wb.y, rcpf_(fmaf((float)pv[5], qb.y, 1.f)), sacc1); \
  sacc0 = fmaf(wb.z, rcpf_(fmaf((float)pv[6], qb.z, 1.f)), sacc0); \
  sacc1 = fmaf(wb.w, rcpf_(fmaf((float)pv[7], qb.w, 1.f)), sacc1); }

// ---------------- the scan ----------------
// grid 256 x 1024 threads; wg owns 2 batch rows; 256 steps; 4 barriers/step.
__global__ __launch_bounds__(1024, 4) void k_scan(
    const _Float16* __restrict__ Ph2, const _Float16* __restrict__ xh,
    const _Float16* __restrict__ w1hcQ, const _Float16* __restrict__ whhG,
    const float* __restrict__ xf, const float* __restrict__ y_hist,
    const float* __restrict__ w2g, const float* __restrict__ Wih,
    const float* __restrict__ bih, const float* __restrict__ bhh,
    const float* __restrict__ fcw, const float* __restrict__ fcb,
    const float* __restrict__ fcfw, const float* __restrict__ fcfb,
    float* __restrict__ out) {
  __shared__ __align__(16) float hc[2][512];        // fp32 [g][ h | c ]
  __shared__ __align__(16) _Float16 hcH[2][520];    // fp16 mirror; h at 0..255, c at 264..519 (pad: khq pair hits disjoint banks)
  __shared__ __align__(16) float Qs[2][256];        // exp(2q)
  __shared__ __align__(16) float spart[2][2][256];  // [eh][g][t]
  __shared__ __align__(16) float ealpha[2][256];
  __shared__ __align__(16) float gfull[2][1024];    // complete gate GEMV values
  __shared__ __align__(16) _Float16 PhL[2][14][256][8]; // 112KB step-invariant Ph2 stage; epilogue cpart alias
  __shared__ __align__(16) float w2l[256];
  __shared__ __align__(16) float Wihl[1024];
  __shared__ __align__(16) float bl[1024];
  __shared__ __align__(16) float xfL[2][256];
  __shared__ __align__(16) float yhL[2][256];
  __shared__ float redA[8], redB[8];

  const int tid = threadIdx.x;
  const int b0 = blockIdx.x * 2;
  const int lo = tid & 255;
  const int wv = tid >> 6, lane = tid & 63;

  // ---- init + one-time Ph2 stage (14 chunk-ids x 2 rows = 112KB) ----
  ((float*)hc)[tid] = 0.f;
  if (tid < 520) {
    hcH[0][tid] = (_Float16)0.f;
    hcH[1][tid] = (_Float16)0.f;
  }
  if (tid < 256) w2l[tid] = w2g[tid];
  Wihl[tid & 1023] = Wih[tid & 1023];
  bl[tid] = bih[tid] + bhh[tid];
  if (tid < 512) {
    int gi = tid >> 8, ti = tid & 255;
    xfL[gi][ti] = xf[(size_t)(b0 + gi) * 256 + ti];
    yhL[gi][ti] = y_hist[(size_t)(b0 + gi) * 256 + ti];
  }
  {
    half8* phl8 = reinterpret_cast<half8*>(&PhL[0][0][0][0]);
    const half8* ph8 = reinterpret_cast<const half8*>(Ph2);
#pragma unroll
    for (int u2 = 0; u2 < 7; ++u2) {
      int slot = u2 * 1024 + tid;         // 0..7167
      int g = slot >= 3584;
      int rem = slot - g * 3584;
      int ci = rem >> 8;                  // 0..13
      int t = rem & 255;
      int cc = (ci < 7) ? (2 * ci) : (16 + 2 * (ci - 7));  // staged chunk ids
      phl8[slot] = ph8[((size_t)(b0 + g) * 32 + cc) * 256 + t];
    }
  }
  __syncthreads();
  float w2sum = 0.f;
  for (int e2 = 0; e2 < 256; ++e2) w2sum += w2l[e2];
  const float fcb0 = fcb[0];
  const float fcwy = fcw[256];

  // per-thread role constants
  // phase A q (tid<512): e = tid>>1, kh = tid&1 (lane-pair k-split), both rows
  const half8* wq2 = reinterpret_cast<const half8*>(w1hcQ) + tid;  // chunk c: wq2[c*512]
  const int khq = tid & 1;
  // phase A gates (tid>=512): u = tid-512; j in {u, u+512}, full k
  const int ug = (tid - 512) & 511;
  const half8* wgJ = reinterpret_cast<const half8*>(whhG) + ug;    // j0: [c*1024], j1: [c*1024+512]
  // scores: thread = (gs = tid>>9, eh = (tid>>8)&1, t = lo), e in [eh*128, +128)
  const int gs = tid >> 9, eh = (tid >> 8) & 1;
  const half8* prow = reinterpret_cast<const half8*>(Ph2) +
                      ((size_t)((b0 + gs) * 32 + eh * 16)) * 256 + lo;
  const half8* phlR = reinterpret_cast<const half8*>(&PhL[0][0][0][0]) +
                      (gs * 14 + eh * 7) * 256 + lo;
  // pointwise / softmax-combine (tid < 512)
  const int gp = (tid >> 8) & 1;

#pragma unroll 1
  for (int s = 0; s < 256; ++s) {
    // ---- phase A: q (lane-pair, both rows) || gates (full-k, 2 j's, both rows) ----
    if (tid < 512) {
      float a0 = 0.f, a1 = 0.f;
      const half8* hp0 = reinterpret_cast<const half8*>(&hcH[0][khq * 264]);
      const half8* hp1 = reinterpret_cast<const half8*>(&hcH[1][khq * 264]);
#pragma unroll 8
      for (int c = 0; c < 32; ++c) {
        half8 w = wq2[c * 512];
        a0 = dot8_(w, hp0[c], a0);   // pad: khq=0/1 on disjoint 4-bank groups
        a1 = dot8_(w, hp1[c], a1);
      }
      a0 += __shfl_xor(a0, 1);       // lane-pair combine: q complete
      a1 += __shfl_xor(a1, 1);
      if (khq == 0) {
        int e = tid >> 1;
        Qs[0][e] = __expf(2.f * a0);
        Qs[1][e] = __expf(2.f * a1);
      }
    } else {
      float ac00 = 0.f, ac01 = 0.f, ac10 = 0.f, ac11 = 0.f;  // [jslot][row]
      const half8* hg0 = reinterpret_cast<const half8*>(&hcH[0][0]);
      const half8* hg1 = reinterpret_cast<const half8*>(&hcH[1][0]);
#pragma unroll 4
      for (int c = 0; c < 32; ++c) {
        half8 h0 = hg0[c];   // broadcast
        half8 h1 = hg1[c];
        half8 w0 = wgJ[c * 1024];
        half8 w1v = wgJ[c * 1024 + 512];
        ac00 = dot8_(w0, h0, ac00);  ac01 = dot8_(w0, h1, ac01);
        ac10 = dot8_(w1v, h0, ac10); ac11 = dot8_(w1v, h1, ac11);
      }
      gfull[0][ug] = ac00;
      gfull[1][ug] = ac01;
      gfull[0][ug + 512] = ac10;
      gfull[1][ug + 512] = ac11;
    }
    __syncthreads();  // B1

    // ---- phase B: scores, e-split 2; 7 chunks LDS + 9 streamed ----
    float sacc0 = 0.f, sacc1 = 0.f;
    {
      const float4* q4 = reinterpret_cast<const float4*>(&Qs[gs][eh * 128]);
      const float4* w4 = reinterpret_cast<const float4*>(&w2l[eh * 128]);
      // issue the 9 global loads first (latency hides under LDS math)
      half8 s1 = prow[1 * 256];
      half8 s3 = prow[3 * 256];
      half8 s5 = prow[5 * 256];
      half8 s7 = prow[7 * 256];
      half8 s9 = prow[9 * 256];
      half8 s11 = prow[11 * 256];
      half8 s13 = prow[13 * 256];
      half8 s14 = prow[14 * 256];
      half8 s15 = prow[15 * 256];
      // staged chunks from LDS (zero latency)
      { half8 l0 = phlR[0 * 256];  SC1(l0, 0) }
      { half8 l2 = phlR[1 * 256];  SC1(l2, 2) }
      { half8 l4 = phlR[2 * 256];  SC1(l4, 4) }
      { half8 l6 = phlR[3 * 256];  SC1(l6, 6) }
      { half8 l8 = phlR[4 * 256];  SC1(l8, 8) }
      { half8 la = phlR[5 * 256];  SC1(la, 10) }
      { half8 lc = phlR[6 * 256];  SC1(lc, 12) }
      // streamed chunks
      SC1(s1, 1)  SC1(s3, 3)  SC1(s5, 5)  SC1(s7, 7)  SC1(s9, 9)
      SC1(s11, 11) SC1(s13, 13) SC1(s14, 14) SC1(s15, 15)
    }
    spart[eh][gs][lo] = sacc0 + sacc1;
    __syncthreads();  // B2

    // ---- phase C: combine + softmax reduce (tid < 512) ----
    if (tid < 512) {
      float sc = w2sum - 2.f * (spart[0][gp][lo] + spart[1][gp][lo]);
      float ea = __expf(sc);  // no max-sub: |sc| <= ~21, fp32-safe
      ealpha[gp][lo] = ea;
      float ef = ea * xfL[gp][lo];
      float es = ea;
#pragma unroll
      for (int off = 32; off > 0; off >>= 1) {
        es += __shfl_xor(es, off);
        ef += __shfl_xor(ef, off);
      }
      if (lane == 0) { redA[wv] = es; redB[wv] = ef; }
    }
    __syncthreads();  // B3

    // ---- phase D: LSTM pointwise (tid < 512) ----
    if (tid < 512) {
      float es = (gp == 0) ? (redA[0] + redA[1] + redA[2] + redA[3])
                           : (redA[4] + redA[5] + redA[6] + redA[7]);
      float ef = (gp == 0) ? (redB[0] + redB[1] + redB[2] + redB[3])
                           : (redB[4] + redB[5] + redB[6] + redB[7]);
      float yt = ef * rcpf_(es) + fmaf(yhL[gp][s], fcwy, fcb0);
      float gi = fmaf(yt, Wihl[lo], bl[lo]) + gfull[gp][lo];
      float gf = fmaf(yt, Wihl[256 + lo], bl[256 + lo]) + gfull[gp][256 + lo];
      float gc = fmaf(yt, Wihl[512 + lo], bl[512 + lo]) + gfull[gp][512 + lo];
      float go = fmaf(yt, Wihl[768 + lo], bl[768 + lo]) + gfull[gp][768 + lo];
      float iv = sigmoidf_(gi), fv = sigmoidf_(gf), gv = tanhf_(gc), ov = sigmoidf_(go);
      float cold = hc[gp][256 + lo];
      float cn = fmaf(fv, cold, iv * gv);
      float hn = ov * tanhf_(cn);
      hc[gp][lo] = hn;
      hc[gp][256 + lo] = cn;
      hcH[gp][lo] = (_Float16)hn;
      hcH[gp][264 + lo] = (_Float16)cn;
    }
    __syncthreads();  // B4
  }

  // ---- epilogue: context from step-255 ealpha, then out = [h|ctx].fcf ----
  // read last-step softmax sums BEFORE redA/redB get reused
  const float rsA = rcpf_(redA[0] + redA[1] + redA[2] + redA[3]);
  const float rsB = rcpf_(redA[4] + redA[5] + redA[6] + redA[7]);

  float* cpartF = reinterpret_cast<float*>(&PhL[0][0][0][0]);  // 32KB alias in 112KB stage
  {
    const int gc = tid >> 9, t16 = (tid >> 5) & 15, l5 = tid & 31;
    const half8* xrow = reinterpret_cast<const half8*>(xh) +
                        ((size_t)(b0 + gc) * 256 + t16 * 16) * 32 + l5;
    float acx[8];
#pragma unroll
    for (int m = 0; m < 8; ++m) acx[m] = 0.f;
#pragma unroll 4
    for (int it = 0; it < 16; ++it) {
      float al = ealpha[gc][t16 * 16 + it];
      half8 xv = xrow[it * 32];
#pragma unroll
      for (int m = 0; m < 8; ++m) acx[m] = fmaf(al, (float)xv[m], acx[m]);
    }
    float* dst = &cpartF[((gc * 16 + t16) * 256) + l5 * 8];
    *reinterpret_cast<float4*>(dst) = *reinterpret_cast<float4*>(&acx[0]);
    *reinterpret_cast<float4*>(dst + 4) = *reinterpret_cast<float4*>(&acx[4]);
  }
  __syncthreads();

  if (tid < 512) {
    float cv = 0.f;
#pragma unroll
    for (int u = 0; u < 16; ++u) cv += cpartF[((gp * 16 + u) * 256) + lo];
    cv *= (gp == 0) ? rsA : rsB;
    float hval = hc[gp][lo];
    float p0 = hval * fcfw[lo] + cv * fcfw[256 + lo];
    float p1 = hval * fcfw[512 + lo] + cv * fcfw[768 + lo];
#pragma unroll
    for (int off = 32; off > 0; off >>= 1) {
      p0 += __shfl_xor(p0, off);
      p1 += __shfl_xor(p1, off);
    }
    if (lane == 0) { redA[wv] = p0; redB[wv] = p1; }
  }
  __syncthreads();
  if (tid < 4) {
    int g2 = tid >> 1, o = tid & 1;
    const float* r = (o == 0) ? redA : redB;
    float v = fcfb[o] + r[g2 * 4 + 0] + r[g2 * 4 + 1] + r[g2 * 4 + 2] + r[g2 * 4 + 3];
    out[(b0 + g2) * 2 + o] = v;
  }
}

extern "C" void kernel_launch(void* const* d_in, const int* in_sizes, int n_in,
                              void* d_out, int out_size, void* d_ws, size_t ws_size,
                              hipStream_t stream) {
  (void)in_sizes; (void)n_in; (void)out_size; (void)ws_size;
  const float* x    = (const float*)d_in[0];
  const float* yh   = (const float*)d_in[1];
  const float* w1   = (const float*)d_in[2];
  const float* b1   = (const float*)d_in[3];
  const float* w2   = (const float*)d_in[4];
  /* d_in[5] attn_b2: softmax-invariant, unused */
  const float* Wih  = (const float*)d_in[6];
  const float* Whh  = (const float*)d_in[7];
  const float* bih  = (const float*)d_in[8];
  const float* bhh  = (const float*)d_in[9];
  const float* fcw  = (const float*)d_in[10];
  const float* fcb  = (const float*)d_in[11];
  const float* fcfw = (const float*)d_in[12];
  const float* fcfb = (const float*)d_in[13];
  float* out = (float*)d_out;

  char* ws = (char*)d_ws;
  _Float16* Ph2   = (_Float16*)(ws);                      // 67108864 B
  _Float16* xh    = (_Float16*)(ws + (size_t)67108864);   // 67108864 B
  float*    wT    = (float*)   (ws + (size_t)134217728);  // 262144 B
  _Float16* w1hcQ = (_Float16*)(ws + (size_t)134479872);  // 262144 B
  _Float16* whhG  = (_Float16*)(ws + (size_t)134742016);  // 524288 B
  float*    xf    = (float*)   (ws + (size_t)135266304);  // 524288 B
  // total: 135790592 B (~129.5 MB)

  k_prep_wT   <<<256,   256, 0, stream>>>(w1, wT);
  k_prep_xh   <<<32768, 256, 0, stream>>>(x, xh);
  k_prep_w1hcQ<<<512,   256, 0, stream>>>(w1, w1hcQ);
  k_prep_whhG <<<1024,  256, 0, stream>>>(Whh, whhG);
  k_xf        <<<8192,  256, 0, stream>>>(x, fcw, xf);
  k_encp      <<<8192,  256, 0, stream>>>(x, wT, b1, Ph2);
  k_scan      <<<256,  1024, 0, stream>>>(Ph2, xh, w1hcQ, whhG, xf, yh, w2, Wih,
                                          bih, bhh, fcw, fcb, fcfw, fcfb, out);
}

// Round 15
// 3652.914 us; speedup vs baseline: 1.6038x; 1.0024x over previous
//
#include <hip/hip_runtime.h>
#include <cstdint>
#include <cstddef>

// Decoder (DA-RNN): B=512, T=256, E=D=256.
// Round 17: base = R16 (verified best, ~3565us k_scan; conflicts fixed, L2-
// resident FETCH 84MB). One structural change, no stream mixing (R15's
// failure mode): scores e-split moves to LANE PAIRS (ehp=tid&1, t=tid>>1) --
// the e-combine becomes one __shfl_xor(sacc,1) in-wave, so ealpha/exp and the
// t-reduce fuse into phase B. spart + phase C die: 3 barriers/step (was 4).
// Freed LDS -> stage 16 even Ph2 chunk-ids (128KB); streamed 9->8 per thread.
// Phase A (q lane-pair + gates full-k) untouched. redA/redB -> 16 wave slots.

typedef _Float16 half8 __attribute__((ext_vector_type(8)));
typedef _Float16 half4v __attribute__((ext_vector_type(4)));
typedef _Float16 half2v __attribute__((ext_vector_type(2)));

__device__ __forceinline__ float rcpf_(float x) { return __builtin_amdgcn_rcpf(x); }
__device__ __forceinline__ float sigmoidf_(float x) { return rcpf_(1.f + __expf(-x)); }
__device__ __forceinline__ float tanhf_(float x) { return 1.f - 2.f * rcpf_(1.f + __expf(2.f * x)); }

#if defined(__has_builtin)
#if __has_builtin(__builtin_amdgcn_fdot2)
#define HAS_FDOT2 1
#endif
#endif
#ifndef HAS_FDOT2
#define HAS_FDOT2 0
#endif

__device__ __forceinline__ float fdot2_(half2v a, half2v b, float c) {
#if HAS_FDOT2
  return __builtin_amdgcn_fdot2(a, b, c, false);
#else
  return fmaf((float)a[0], (float)b[0], fmaf((float)a[1], (float)b[1], c));
#endif
}

__device__ __forceinline__ float dot8_(half8 w, half8 h, float acc) {
  acc = fdot2_(__builtin_shufflevector(w, w, 0, 1), __builtin_shufflevector(h, h, 0, 1), acc);
  acc = fdot2_(__builtin_shufflevector(w, w, 2, 3), __builtin_shufflevector(h, h, 2, 3), acc);
  acc = fdot2_(__builtin_shufflevector(w, w, 4, 5), __builtin_shufflevector(h, h, 4, 5), acc);
  acc = fdot2_(__builtin_shufflevector(w, w, 6, 7), __builtin_shufflevector(h, h, 6, 7), acc);
  return acc;
}

// ---------------- prep kernels ----------------

// wT[e*256+f] = attn_w1[f*768 + 512 + e]   (transposed w1_enc, fp32)
__global__ void k_prep_wT(const float* __restrict__ w1, float* __restrict__ wT) {
  int id = blockIdx.x * 256 + threadIdx.x;
  int e = id >> 8, f = id & 255;
  wT[id] = w1[f * 768 + 512 + e];
}

// x -> fp16 (4 elems/thread), layout unchanged [b][t][e]
__global__ void k_prep_xh(const float* __restrict__ x, _Float16* __restrict__ xh) {
  int id = blockIdx.x * 256 + threadIdx.x;
  float4 v = reinterpret_cast<const float4*>(x)[id];
  half4v h;
  h[0] = (_Float16)v.x; h[1] = (_Float16)v.y; h[2] = (_Float16)v.z; h[3] = (_Float16)v.w;
  reinterpret_cast<half4v*>(xh)[id] = h;
}

// w1hcP2[(c*512 + e*2 + kh)*8 + m] = w1[e*768 + kh*256 + c*8 + m], c in [0,32)
// (k_scan q-thread tid = e*2+kh reads chunk c at half8 index c*512 + tid)
__global__ void k_prep_w1hcQ(const float* __restrict__ w1, _Float16* __restrict__ o) {
  int id = blockIdx.x * 256 + threadIdx.x;  // 131072 total
  int m = id & 7, lane = (id >> 3) & 511, c = id >> 12;
  int e = lane >> 1, kh = lane & 1;
  o[id] = (_Float16)w1[e * 768 + kh * 256 + c * 8 + m];
}

// whhJ[(c*1024 + j)*8 + m] = Whh[j*256 + c*8 + m], c in [0,32)
// (gates thread u handles j in {u, u+512}, both lane-consecutive)
__global__ void k_prep_whhG(const float* __restrict__ whh, _Float16* __restrict__ o) {
  int id = blockIdx.x * 256 + threadIdx.x;  // 262144 total
  int m = id & 7, j = (id >> 3) & 1023, c = id >> 13;
  o[id] = (_Float16)whh[j * 256 + c * 8 + m];
}

// xf[b*256+t] = sum_e x[b,t,e] * fcw[e]   (fp32)
__global__ __launch_bounds__(256) void k_xf(const float* __restrict__ x,
                                            const float* __restrict__ fcw,
                                            float* __restrict__ xf) {
  __shared__ float xl[16][256];
  __shared__ float fw[256];
  __shared__ float part[16][17];
  const int tid = threadIdx.x;
  const int m0 = blockIdx.x * 16;
  fw[tid] = fcw[tid];
#pragma unroll
  for (int r = 0; r < 16; ++r) xl[r][tid] = x[(size_t)(m0 + r) * 256 + tid];
  __syncthreads();
  int r = tid >> 4, p = tid & 15;
  float s = 0.f;
#pragma unroll
  for (int u = 0; u < 16; ++u) s = fmaf(xl[r][p * 16 + u], fw[p * 16 + u], s);
  part[r][p] = s;
  __syncthreads();
  if (tid < 16) {
    float t = 0.f;
#pragma unroll
    for (int p2 = 0; p2 < 16; ++p2) t += part[tid][p2];
    xf[m0 + tid] = t;
  }
}

// enc_proj GEMM + bias, store P=exp(2*encp) fp16 in layout [b][e/8][t][e%8]
__global__ __launch_bounds__(256) void k_encp(const float* __restrict__ x,
                                              const float* __restrict__ wT,
                                              const float* __restrict__ b1,
                                              _Float16* __restrict__ Ph2) {
  __shared__ __align__(16) float xl[16][256];
  const int tid = threadIdx.x;
  const int m0 = blockIdx.x * 16;
#pragma unroll
  for (int r = 0; r < 16; ++r) xl[r][tid] = x[(size_t)(m0 + r) * 256 + tid];
  __syncthreads();
  float acc[16];
#pragma unroll
  for (int r = 0; r < 16; ++r) acc[r] = 0.f;
  for (int e = 0; e < 256; e += 4) {
    float w0 = wT[(e + 0) * 256 + tid];
    float w1_ = wT[(e + 1) * 256 + tid];
    float w2_ = wT[(e + 2) * 256 + tid];
    float w3_ = wT[(e + 3) * 256 + tid];
#pragma unroll
    for (int r = 0; r < 16; ++r) {
      float4 xv = *reinterpret_cast<const float4*>(&xl[r][e]);
      acc[r] = fmaf(xv.x, w0, acc[r]);
      acc[r] = fmaf(xv.y, w1_, acc[r]);
      acc[r] = fmaf(xv.z, w2_, acc[r]);
      acc[r] = fmaf(xv.w, w3_, acc[r]);
    }
  }
  float bb = b1[tid];
  const int e = tid;
#pragma unroll
  for (int r = 0; r < 16; ++r) {
    int m = m0 + r, b = m >> 8, t = m & 255;
    float p = __expf(2.f * (acc[r] + bb));
    Ph2[((size_t)(b * 32 + (e >> 3)) * 256 + t) * 8 + (e & 7)] = (_Float16)p;
  }
}

#define SC1(pv, c) { \
  float4 qa = q4[2*(c)], wa = w4[2*(c)]; \
  sacc0 = fmaf(wa.x, rcpf_(fmaf((float)pv[0], qa.x, 1.f)), sacc0); \
  sacc1 = fmaf(wa.y, rcpf_(fmaf((float)pv[1], qa.y, 1.f)), sacc1); \
  sacc0 = fmaf(wa.z, rcpf_(fmaf((float)pv[2], qa.z, 1.f)), sacc0); \
  sacc1 = fmaf(wa.w, rcpf_(fmaf((float)pv[3], qa.w, 1.f)), sacc1); \
  float4 qb = q4[2*(c)+1], wb = w4[2*(c)+1]; \
  sacc0 = fmaf(wb.x, rcpf_(fmaf((float)pv[4], qb.x, 1.f)), sacc0); \
  sacc1 = fmaf(wb.y, rcpf_(fmaf((float)pv[5], qb.y, 1.f)), sacc1); \
  sacc0 = fmaf(wb.z, rcpf_(fmaf((float)pv[6], qb.z, 1.f)), sacc0); \
  sacc1 = fmaf(wb.w, rcpf_(fmaf((float)pv[7], qb.w, 1.f)), sacc1); }

// ---------------- the scan ----------------
// grid 256 x 1024 threads; wg owns 2 batch rows; 256 steps; 3 barriers/step.
__global__ __launch_bounds__(1024, 4) void k_scan(
    const _Float16* __restrict__ Ph2, const _Float16* __restrict__ xh,
    const _Float16* __restrict__ w1hcQ, const _Float16* __restrict__ whhG,
    const float* __restrict__ xf, const float* __restrict__ y_hist,
    const float* __restrict__ w2g, const float* __restrict__ Wih,
    const float* __restrict__ bih, const float* __restrict__ bhh,
    const float* __restrict__ fcw, const float* __restrict__ fcb,
    const float* __restrict__ fcfw, const float* __restrict__ fcfb,
    float* __restrict__ out) {
  __shared__ __align__(16) float hc[2][512];        // fp32 [g][ h | c ]
  __shared__ __align__(16) _Float16 hcH[2][520];    // fp16 mirror; h at 0..255, c at 264..519 (pad: khq pair on disjoint banks)
  __shared__ __align__(16) float Qs[2][256];        // exp(2q)
  __shared__ __align__(16) float ealpha[2][256];
  __shared__ __align__(16) float gfull[2][1024];    // complete gate GEMV values
  __shared__ __align__(16) _Float16 PhL[2][16][256][8]; // 128KB: even Ph2 chunk-ids staged once; epilogue cpart alias
  __shared__ __align__(16) float w2l[256];
  __shared__ __align__(16) float Wihl[1024];
  __shared__ __align__(16) float bl[1024];
  __shared__ __align__(16) float xfL[2][256];
  __shared__ __align__(16) float yhL[2][256];
  __shared__ float redA[16], redB[16];

  const int tid = threadIdx.x;
  const int b0 = blockIdx.x * 2;
  const int lo = tid & 255;
  const int wv = tid >> 6, lane = tid & 63;

  // ---- init + one-time Ph2 stage (16 even chunk-ids x 2 rows = 128KB) ----
  ((float*)hc)[tid] = 0.f;
  if (tid < 520) {
    hcH[0][tid] = (_Float16)0.f;
    hcH[1][tid] = (_Float16)0.f;
  }
  if (tid < 256) w2l[tid] = w2g[tid];
  Wihl[tid & 1023] = Wih[tid & 1023];
  bl[tid] = bih[tid] + bhh[tid];
  if (tid < 512) {
    int gi = tid >> 8, ti = tid & 255;
    xfL[gi][ti] = xf[(size_t)(b0 + gi) * 256 + ti];
    yhL[gi][ti] = y_hist[(size_t)(b0 + gi) * 256 + ti];
  }
  {
    half8* phl8 = reinterpret_cast<half8*>(&PhL[0][0][0][0]);
    const half8* ph8 = reinterpret_cast<const half8*>(Ph2);
#pragma unroll
    for (int u2 = 0; u2 < 8; ++u2) {
      int slot = u2 * 1024 + tid;         // 0..8191
      int g = slot >= 4096;
      int rem = slot - g * 4096;
      int ci = rem >> 8;                  // 0..15
      int t = rem & 255;
      int cc = 2 * ci;                    // staged chunk ids: all even
      phl8[slot] = ph8[((size_t)(b0 + g) * 32 + cc) * 256 + t];
    }
  }
  __syncthreads();
  float w2sum = 0.f;
  for (int e2 = 0; e2 < 256; ++e2) w2sum += w2l[e2];
  const float fcb0 = fcb[0];
  const float fcwy = fcw[256];

  // per-thread role constants
  // phase A q (tid<512): e = tid>>1, khq = tid&1 (lane-pair k-split), both rows
  const half8* wq2 = reinterpret_cast<const half8*>(w1hcQ) + tid;  // chunk c: wq2[c*512]
  const int khq = tid & 1;
  // phase A gates (tid>=512): u = tid-512; j in {u, u+512}, full k
  const int ug = (tid - 512) & 511;
  const half8* wgJ = reinterpret_cast<const half8*>(whhG) + ug;    // j0: [c*1024], j1: [c*1024+512]
  // phase B scores: gs = tid>>9, t = (tid>>1)&255, ehp = tid&1 (lane-pair e-split)
  const int gs = tid >> 9, tp = (tid >> 1) & 255, ehp = tid & 1;
  const half8* prowP = reinterpret_cast<const half8*>(Ph2) +
                       ((size_t)((b0 + gs) * 32 + ehp * 16)) * 256 + tp;
  const half8* phlRP = reinterpret_cast<const half8*>(&PhL[0][0][0][0]) +
                       (gs * 16 + ehp * 8) * 256 + tp;
  // phase D pointwise (tid < 512)
  const int gp = (tid >> 8) & 1;

#pragma unroll 1
  for (int s = 0; s < 256; ++s) {
    // ---- phase A: q (lane-pair, both rows) || gates (full-k, 2 j's, both rows) ----
    if (tid < 512) {
      float a0 = 0.f, a1 = 0.f;
      const half8* hp0 = reinterpret_cast<const half8*>(&hcH[0][khq * 264]);
      const half8* hp1 = reinterpret_cast<const half8*>(&hcH[1][khq * 264]);
#pragma unroll 8
      for (int c = 0; c < 32; ++c) {
        half8 w = wq2[c * 512];
        a0 = dot8_(w, hp0[c], a0);   // pad: khq=0/1 on disjoint 4-bank groups
        a1 = dot8_(w, hp1[c], a1);
      }
      a0 += __shfl_xor(a0, 1);       // lane-pair combine: q complete
      a1 += __shfl_xor(a1, 1);
      if (khq == 0) {
        int e = tid >> 1;
        Qs[0][e] = __expf(2.f * a0);
        Qs[1][e] = __expf(2.f * a1);
      }
    } else {
      float ac00 = 0.f, ac01 = 0.f, ac10 = 0.f, ac11 = 0.f;  // [jslot][row]
      const half8* hg0 = reinterpret_cast<const half8*>(&hcH[0][0]);
      const half8* hg1 = reinterpret_cast<const half8*>(&hcH[1][0]);
#pragma unroll 4
      for (int c = 0; c < 32; ++c) {
        half8 h0 = hg0[c];   // broadcast
        half8 h1 = hg1[c];
        half8 w0 = wgJ[c * 1024];
        half8 w1v = wgJ[c * 1024 + 512];
        ac00 = dot8_(w0, h0, ac00);  ac01 = dot8_(w0, h1, ac01);
        ac10 = dot8_(w1v, h0, ac10); ac11 = dot8_(w1v, h1, ac11);
      }
      gfull[0][ug] = ac00;
      gfull[1][ug] = ac01;
      gfull[0][ug + 512] = ac10;
      gfull[1][ug + 512] = ac11;
    }
    __syncthreads();  // B1

    // ---- phase B: scores (lane-pair e-split) + fused softmax reduce, all threads ----
    {
      float sacc0 = 0.f, sacc1 = 0.f;
      const float4* q4 = reinterpret_cast<const float4*>(&Qs[gs][ehp * 128]);
      const float4* w4 = reinterpret_cast<const float4*>(&w2l[ehp * 128]);
      // 8 streamed odd local chunks: issue first (latency hides under LDS math)
      half8 s1 = prowP[1 * 256];
      half8 s3 = prowP[3 * 256];
      half8 s5 = prowP[5 * 256];
      half8 s7 = prowP[7 * 256];
      half8 s9 = prowP[9 * 256];
      half8 s11 = prowP[11 * 256];
      half8 s13 = prowP[13 * 256];
      half8 s15 = prowP[15 * 256];
      // 8 staged even local chunks from LDS (2-way reads: free)
      { half8 l = phlRP[0 * 256]; SC1(l, 0) }
      { half8 l = phlRP[1 * 256]; SC1(l, 2) }
      { half8 l = phlRP[2 * 256]; SC1(l, 4) }
      { half8 l = phlRP[3 * 256]; SC1(l, 6) }
      { half8 l = phlRP[4 * 256]; SC1(l, 8) }
      { half8 l = phlRP[5 * 256]; SC1(l, 10) }
      { half8 l = phlRP[6 * 256]; SC1(l, 12) }
      { half8 l = phlRP[7 * 256]; SC1(l, 14) }
      // streamed odd local chunks
      SC1(s1, 1)  SC1(s3, 3)  SC1(s5, 5)  SC1(s7, 7)
      SC1(s9, 9)  SC1(s11, 11) SC1(s13, 13) SC1(s15, 15)
      float sacc = sacc0 + sacc1;
      sacc += __shfl_xor(sacc, 1);   // lane-pair e-combine: full-e sum
      float ea = __expf(w2sum - 2.f * sacc);  // no max-sub: |sc| <= ~21, fp32-safe
      if (ehp == 0) ealpha[gs][tp] = ea;
      float es = (ehp == 0) ? ea : 0.f;       // avoid double-count in t-reduce
      float ef = es * xfL[gs][tp];
#pragma unroll
      for (int off = 32; off > 0; off >>= 1) {
        es += __shfl_xor(es, off);
        ef += __shfl_xor(ef, off);
      }
      if (lane == 0) { redA[wv] = es; redB[wv] = ef; }  // wv 0..7: row0, 8..15: row1
    }
    __syncthreads();  // B2

    // ---- phase D: LSTM pointwise (tid < 512) ----
    if (tid < 512) {
      const int rb = gp * 8;
      float es = redA[rb + 0] + redA[rb + 1] + redA[rb + 2] + redA[rb + 3] +
                 redA[rb + 4] + redA[rb + 5] + redA[rb + 6] + redA[rb + 7];
      float ef = redB[rb + 0] + redB[rb + 1] + redB[rb + 2] + redB[rb + 3] +
                 redB[rb + 4] + redB[rb + 5] + redB[rb + 6] + redB[rb + 7];
      float yt = ef * rcpf_(es) + fmaf(yhL[gp][s], fcwy, fcb0);
      float gi = fmaf(yt, Wihl[lo], bl[lo]) + gfull[gp][lo];
      float gf = fmaf(yt, Wihl[256 + lo], bl[256 + lo]) + gfull[gp][256 + lo];
      float gc = fmaf(yt, Wihl[512 + lo], bl[512 + lo]) + gfull[gp][512 + lo];
      float go = fmaf(yt, Wihl[768 + lo], bl[768 + lo]) + gfull[gp][768 + lo];
      float iv = sigmoidf_(gi), fv = sigmoidf_(gf), gv = tanhf_(gc), ov = sigmoidf_(go);
      float cold = hc[gp][256 + lo];
      float cn = fmaf(fv, cold, iv * gv);
      float hn = ov * tanhf_(cn);
      hc[gp][lo] = hn;
      hc[gp][256 + lo] = cn;
      hcH[gp][lo] = (_Float16)hn;
      hcH[gp][264 + lo] = (_Float16)cn;
    }
    __syncthreads();  // B3
  }

  // ---- epilogue: context from step-255 ealpha, then out = [h|ctx].fcf ----
  // read last-step softmax sums BEFORE redA/redB get reused
  const float rsA = rcpf_(redA[0] + redA[1] + redA[2] + redA[3] +
                          redA[4] + redA[5] + redA[6] + redA[7]);
  const float rsB = rcpf_(redA[8] + redA[9] + redA[10] + redA[11] +
                          redA[12] + redA[13] + redA[14] + redA[15]);

  float* cpartF = reinterpret_cast<float*>(&PhL[0][0][0][0]);  // 32KB alias in 128KB stage
  {
    const int gc = tid >> 9, t16 = (tid >> 5) & 15, l5 = tid & 31;
    const half8* xrow = reinterpret_cast<const half8*>(xh) +
                        ((size_t)(b0 + gc) * 256 + t16 * 16) * 32 + l5;
    float acx[8];
#pragma unroll
    for (int m = 0; m < 8; ++m) acx[m] = 0.f;
#pragma unroll 4
    for (int it = 0; it < 16; ++it) {
      float al = ealpha[gc][t16 * 16 + it];
      half8 xv = xrow[it * 32];
#pragma unroll
      for (int m = 0; m < 8; ++m) acx[m] = fmaf(al, (float)xv[m], acx[m]);
    }
    float* dst = &cpartF[((gc * 16 + t16) * 256) + l5 * 8];
    *reinterpret_cast<float4*>(dst) = *reinterpret_cast<float4*>(&acx[0]);
    *reinterpret_cast<float4*>(dst + 4) = *reinterpret_cast<float4*>(&acx[4]);
  }
  __syncthreads();

  if (tid < 512) {
    float cv = 0.f;
#pragma unroll
    for (int u = 0; u < 16; ++u) cv += cpartF[((gp * 16 + u) * 256) + lo];
    cv *= (gp == 0) ? rsA : rsB;
    float hval = hc[gp][lo];
    float p0 = hval * fcfw[lo] + cv * fcfw[256 + lo];
    float p1 = hval * fcfw[512 + lo] + cv * fcfw[768 + lo];
#pragma unroll
    for (int off = 32; off > 0; off >>= 1) {
      p0 += __shfl_xor(p0, off);
      p1 += __shfl_xor(p1, off);
    }
    if (lane == 0) { redA[wv] = p0; redB[wv] = p1; }
  }
  __syncthreads();
  if (tid < 4) {
    int g2 = tid >> 1, o = tid & 1;
    const float* r = (o == 0) ? redA : redB;
    float v = fcfb[o] + r[g2 * 4 + 0] + r[g2 * 4 + 1] + r[g2 * 4 + 2] + r[g2 * 4 + 3];
    out[(b0 + g2) * 2 + o] = v;
  }
}

extern "C" void kernel_launch(void* const* d_in, const int* in_sizes, int n_in,
                              void* d_out, int out_size, void* d_ws, size_t ws_size,
                              hipStream_t stream) {
  (void)in_sizes; (void)n_in; (void)out_size; (void)ws_size;
  const float* x    = (const float*)d_in[0];
  const float* yh   = (const float*)d_in[1];
  const float* w1   = (const float*)d_in[2];
  const float* b1   = (const float*)d_in[3];
  const float* w2   = (const float*)d_in[4];
  /* d_in[5] attn_b2: softmax-invariant, unused */
  const float* Wih  = (const float*)d_in[6];
  const float* Whh  = (const float*)d_in[7];
  const float* bih  = (const float*)d_in[8];
  const float* bhh  = (const float*)d_in[9];
  const float* fcw  = (const float*)d_in[10];
  const float* fcb  = (const float*)d_in[11];
  const float* fcfw = (const float*)d_in[12];
  const float* fcfb = (const float*)d_in[13];
  float* out = (float*)d_out;

  char* ws = (char*)d_ws;
  _Float16* Ph2   = (_Float16*)(ws);                      // 67108864 B
  _Float16* xh    = (_Float16*)(ws + (size_t)67108864);   // 67108864 B
  float*    wT    = (float*)   (ws + (size_t)134217728);  // 262144 B
  _Float16* w1hcQ = (_Float16*)(ws + (size_t)134479872);  // 262144 B
  _Float16* whhG  = (_Float16*)(ws + (size_t)134742016);  // 524288 B
  float*    xf    = (float*)   (ws + (size_t)135266304);  // 524288 B
  // total: 135790592 B (~129.5 MB)

  k_prep_wT   <<<256,   256, 0, stream>>>(w1, wT);
  k_prep_xh   <<<32768, 256, 0, stream>>>(x, xh);
  k_prep_w1hcQ<<<512,   256, 0, stream>>>(w1, w1hcQ);
  k_prep_whhG <<<1024,  256, 0, stream>>>(Whh, whhG);
  k_xf        <<<8192,  256, 0, stream>>>(x, fcw, xf);
  k_encp      <<<8192,  256, 0, stream>>>(x, wT, b1, Ph2);
  k_scan      <<<256,  1024, 0, stream>>>(Ph2, xh, w1hcQ, whhG, xf, yh, w2, Wih,
                                          bih, bhh, fcw, fcb, fcfw, fcfb, out);
}

// Round 16
// 3423.870 us; speedup vs baseline: 1.7111x; 1.0669x over previous
//
#include <hip/hip_runtime.h>
#include <cstdint>
#include <cstddef>

// Decoder (DA-RNN): B=512, T=256, E=D=256.
// Round 18: base = R17 (3-barrier lane-pair structure). Fix its tripped
// canary: 3.02e8 bank-conflict cycles from phase-B lane-pair reads whose
// ehp=0/1 bases are 32KB (PhL) / 512B (Qs, w2l) apart == 0 mod 128B -> every
// ds_read_b128/broadcast was 2-way same-bank. Same remedy class as R16's
// hcH pad: (1) Qs[2][264], data at e+(e>>7)*4 (ehp=1 base at +528B = +4
// banks); (2) w2l[264] same; (3) PhL regions padded to 2049 half8
// ([2][2][16392] halfs) -> ehp=1 region base at +1 half8 = +4 banks.
// Nothing else changes. LDS ~163.4KB (fits 160KiB=163840B budget).

typedef _Float16 half8 __attribute__((ext_vector_type(8)));
typedef _Float16 half4v __attribute__((ext_vector_type(4)));
typedef _Float16 half2v __attribute__((ext_vector_type(2)));

__device__ __forceinline__ float rcpf_(float x) { return __builtin_amdgcn_rcpf(x); }
__device__ __forceinline__ float sigmoidf_(float x) { return rcpf_(1.f + __expf(-x)); }
__device__ __forceinline__ float tanhf_(float x) { return 1.f - 2.f * rcpf_(1.f + __expf(2.f * x)); }

#if defined(__has_builtin)
#if __has_builtin(__builtin_amdgcn_fdot2)
#define HAS_FDOT2 1
#endif
#endif
#ifndef HAS_FDOT2
#define HAS_FDOT2 0
#endif

__device__ __forceinline__ float fdot2_(half2v a, half2v b, float c) {
#if HAS_FDOT2
  return __builtin_amdgcn_fdot2(a, b, c, false);
#else
  return fmaf((float)a[0], (float)b[0], fmaf((float)a[1], (float)b[1], c));
#endif
}

__device__ __forceinline__ float dot8_(half8 w, half8 h, float acc) {
  acc = fdot2_(__builtin_shufflevector(w, w, 0, 1), __builtin_shufflevector(h, h, 0, 1), acc);
  acc = fdot2_(__builtin_shufflevector(w, w, 2, 3), __builtin_shufflevector(h, h, 2, 3), acc);
  acc = fdot2_(__builtin_shufflevector(w, w, 4, 5), __builtin_shufflevector(h, h, 4, 5), acc);
  acc = fdot2_(__builtin_shufflevector(w, w, 6, 7), __builtin_shufflevector(h, h, 6, 7), acc);
  return acc;
}

// ---------------- prep kernels ----------------

// wT[e*256+f] = attn_w1[f*768 + 512 + e]   (transposed w1_enc, fp32)
__global__ void k_prep_wT(const float* __restrict__ w1, float* __restrict__ wT) {
  int id = blockIdx.x * 256 + threadIdx.x;
  int e = id >> 8, f = id & 255;
  wT[id] = w1[f * 768 + 512 + e];
}

// x -> fp16 (4 elems/thread), layout unchanged [b][t][e]
__global__ void k_prep_xh(const float* __restrict__ x, _Float16* __restrict__ xh) {
  int id = blockIdx.x * 256 + threadIdx.x;
  float4 v = reinterpret_cast<const float4*>(x)[id];
  half4v h;
  h[0] = (_Float16)v.x; h[1] = (_Float16)v.y; h[2] = (_Float16)v.z; h[3] = (_Float16)v.w;
  reinterpret_cast<half4v*>(xh)[id] = h;
}

// w1hcP2[(c*512 + e*2 + kh)*8 + m] = w1[e*768 + kh*256 + c*8 + m], c in [0,32)
// (k_scan q-thread tid = e*2+kh reads chunk c at half8 index c*512 + tid)
__global__ void k_prep_w1hcQ(const float* __restrict__ w1, _Float16* __restrict__ o) {
  int id = blockIdx.x * 256 + threadIdx.x;  // 131072 total
  int m = id & 7, lane = (id >> 3) & 511, c = id >> 12;
  int e = lane >> 1, kh = lane & 1;
  o[id] = (_Float16)w1[e * 768 + kh * 256 + c * 8 + m];
}

// whhJ[(c*1024 + j)*8 + m] = Whh[j*256 + c*8 + m], c in [0,32)
// (gates thread u handles j in {u, u+512}, both lane-consecutive)
__global__ void k_prep_whhG(const float* __restrict__ whh, _Float16* __restrict__ o) {
  int id = blockIdx.x * 256 + threadIdx.x;  // 262144 total
  int m = id & 7, j = (id >> 3) & 1023, c = id >> 13;
  o[id] = (_Float16)whh[j * 256 + c * 8 + m];
}

// xf[b*256+t] = sum_e x[b,t,e] * fcw[e]   (fp32)
__global__ __launch_bounds__(256) void k_xf(const float* __restrict__ x,
                                            const float* __restrict__ fcw,
                                            float* __restrict__ xf) {
  __shared__ float xl[16][256];
  __shared__ float fw[256];
  __shared__ float part[16][17];
  const int tid = threadIdx.x;
  const int m0 = blockIdx.x * 16;
  fw[tid] = fcw[tid];
#pragma unroll
  for (int r = 0; r < 16; ++r) xl[r][tid] = x[(size_t)(m0 + r) * 256 + tid];
  __syncthreads();
  int r = tid >> 4, p = tid & 15;
  float s = 0.f;
#pragma unroll
  for (int u = 0; u < 16; ++u) s = fmaf(xl[r][p * 16 + u], fw[p * 16 + u], s);
  part[r][p] = s;
  __syncthreads();
  if (tid < 16) {
    float t = 0.f;
#pragma unroll
    for (int p2 = 0; p2 < 16; ++p2) t += part[tid][p2];
    xf[m0 + tid] = t;
  }
}

// enc_proj GEMM + bias, store P=exp(2*encp) fp16 in layout [b][e/8][t][e%8]
__global__ __launch_bounds__(256) void k_encp(const float* __restrict__ x,
                                              const float* __restrict__ wT,
                                              const float* __restrict__ b1,
                                              _Float16* __restrict__ Ph2) {
  __shared__ __align__(16) float xl[16][256];
  const int tid = threadIdx.x;
  const int m0 = blockIdx.x * 16;
#pragma unroll
  for (int r = 0; r < 16; ++r) xl[r][tid] = x[(size_t)(m0 + r) * 256 + tid];
  __syncthreads();
  float acc[16];
#pragma unroll
  for (int r = 0; r < 16; ++r) acc[r] = 0.f;
  for (int e = 0; e < 256; e += 4) {
    float w0 = wT[(e + 0) * 256 + tid];
    float w1_ = wT[(e + 1) * 256 + tid];
    float w2_ = wT[(e + 2) * 256 + tid];
    float w3_ = wT[(e + 3) * 256 + tid];
#pragma unroll
    for (int r = 0; r < 16; ++r) {
      float4 xv = *reinterpret_cast<const float4*>(&xl[r][e]);
      acc[r] = fmaf(xv.x, w0, acc[r]);
      acc[r] = fmaf(xv.y, w1_, acc[r]);
      acc[r] = fmaf(xv.z, w2_, acc[r]);
      acc[r] = fmaf(xv.w, w3_, acc[r]);
    }
  }
  float bb = b1[tid];
  const int e = tid;
#pragma unroll
  for (int r = 0; r < 16; ++r) {
    int m = m0 + r, b = m >> 8, t = m & 255;
    float p = __expf(2.f * (acc[r] + bb));
    Ph2[((size_t)(b * 32 + (e >> 3)) * 256 + t) * 8 + (e & 7)] = (_Float16)p;
  }
}

#define SC1(pv, c) { \
  float4 qa = q4[2*(c)], wa = w4[2*(c)]; \
  sacc0 = fmaf(wa.x, rcpf_(fmaf((float)pv[0], qa.x, 1.f)), sacc0); \
  sacc1 = fmaf(wa.y, rcpf_(fmaf((float)pv[1], qa.y, 1.f)), sacc1); \
  sacc0 = fmaf(wa.z, rcpf_(fmaf((float)pv[2], qa.z, 1.f)), sacc0); \
  sacc1 = fmaf(wa.w, rcpf_(fmaf((float)pv[3], qa.w, 1.f)), sacc1); \
  float4 qb = q4[2*(c)+1], wb = w4[2*(c)+1]; \
  sacc0 = fmaf(wb.x, rcpf_(fmaf((float)pv[4], qb.x, 1.f)), sacc0); \
  sacc1 = fmaf(wb.y, rcpf_(fmaf((float)pv[5], qb.y, 1.f)), sacc1); \
  sacc0 = fmaf(wb.z, rcpf_(fmaf((float)pv[6], qb.z, 1.f)), sacc0); \
  sacc1 = fmaf(wb.w, rcpf_(fmaf((float)pv[7], qb.w, 1.f)), sacc1); }

// ---------------- the scan ----------------
// grid 256 x 1024 threads; wg owns 2 batch rows; 256 steps; 3 barriers/step.
__global__ __launch_bounds__(1024, 4) void k_scan(
    const _Float16* __restrict__ Ph2, const _Float16* __restrict__ xh,
    const _Float16* __restrict__ w1hcQ, const _Float16* __restrict__ whhG,
    const float* __restrict__ xf, const float* __restrict__ y_hist,
    const float* __restrict__ w2g, const float* __restrict__ Wih,
    const float* __restrict__ bih, const float* __restrict__ bhh,
    const float* __restrict__ fcw, const float* __restrict__ fcb,
    const float* __restrict__ fcfw, const float* __restrict__ fcfb,
    float* __restrict__ out) {
  __shared__ __align__(16) float hc[2][512];        // fp32 [g][ h | c ]
  __shared__ __align__(16) _Float16 hcH[2][520];    // fp16 mirror; h at 0..255, c at 264..519
  __shared__ __align__(16) float Qs[2][264];        // exp(2q); data at e+(e>>7)*4 (ehp pad)
  __shared__ __align__(16) float ealpha[2][256];
  __shared__ __align__(16) float gfull[2][1024];    // complete gate GEMV values
  __shared__ __align__(16) _Float16 PhL[2][2][16392]; // staged even Ph2 chunks; 2049 half8/region (ehp pad)
  __shared__ __align__(16) float w2l[264];          // data at f+(f>>7)*4 (ehp pad)
  __shared__ __align__(16) float Wihl[1024];
  __shared__ __align__(16) float bl[1024];
  __shared__ __align__(16) float xfL[2][256];
  __shared__ __align__(16) float yhL[2][256];
  __shared__ float redA[16], redB[16];

  const int tid = threadIdx.x;
  const int b0 = blockIdx.x * 2;
  const int lo = tid & 255;
  const int wv = tid >> 6, lane = tid & 63;

  // ---- init + one-time Ph2 stage (16 even chunk-ids x 2 rows, padded regions) ----
  ((float*)hc)[tid] = 0.f;
  if (tid < 520) {
    hcH[0][tid] = (_Float16)0.f;
    hcH[1][tid] = (_Float16)0.f;
  }
  if (tid < 256) w2l[tid + ((tid >> 7) << 2)] = w2g[tid];
  Wihl[tid & 1023] = Wih[tid & 1023];
  bl[tid] = bih[tid] + bhh[tid];
  if (tid < 512) {
    int gi = tid >> 8, ti = tid & 255;
    xfL[gi][ti] = xf[(size_t)(b0 + gi) * 256 + ti];
    yhL[gi][ti] = y_hist[(size_t)(b0 + gi) * 256 + ti];
  }
  {
    half8* phl8 = reinterpret_cast<half8*>(&PhL[0][0][0]);
    const half8* ph8 = reinterpret_cast<const half8*>(Ph2);
#pragma unroll
    for (int u2 = 0; u2 < 8; ++u2) {
      int slot = u2 * 1024 + tid;         // 0..8191
      int g = slot >> 12;
      int rem = slot & 4095;
      int eh = rem >> 11;
      int rem2 = rem & 2047;
      int ci = rem2 >> 8;                 // 0..7 (local even chunk)
      int t = rem2 & 255;
      int cc = eh * 16 + 2 * ci;          // global chunk id (even)
      phl8[(g * 2 + eh) * 2049 + ci * 256 + t] =
          ph8[((size_t)(b0 + g) * 32 + cc) * 256 + t];
    }
  }
  __syncthreads();
  float w2sum = 0.f;
  for (int e2 = 0; e2 < 256; ++e2) w2sum += w2l[e2 + ((e2 >> 7) << 2)];
  const float fcb0 = fcb[0];
  const float fcwy = fcw[256];

  // per-thread role constants
  // phase A q (tid<512): e = tid>>1, khq = tid&1 (lane-pair k-split), both rows
  const half8* wq2 = reinterpret_cast<const half8*>(w1hcQ) + tid;  // chunk c: wq2[c*512]
  const int khq = tid & 1;
  // phase A gates (tid>=512): u = tid-512; j in {u, u+512}, full k
  const int ug = (tid - 512) & 511;
  const half8* wgJ = reinterpret_cast<const half8*>(whhG) + ug;    // j0: [c*1024], j1: [c*1024+512]
  // phase B scores: gs = tid>>9, t = (tid>>1)&255, ehp = tid&1 (lane-pair e-split)
  const int gs = tid >> 9, tp = (tid >> 1) & 255, ehp = tid & 1;
  const half8* prowP = reinterpret_cast<const half8*>(Ph2) +
                       ((size_t)((b0 + gs) * 32 + ehp * 16)) * 256 + tp;
  const half8* phlRP = reinterpret_cast<const half8*>(&PhL[0][0][0]) +
                       (gs * 2 + ehp) * 2049 + tp;
  // phase D pointwise (tid < 512)
  const int gp = (tid >> 8) & 1;

#pragma unroll 1
  for (int s = 0; s < 256; ++s) {
    // ---- phase A: q (lane-pair, both rows) || gates (full-k, 2 j's, both rows) ----
    if (tid < 512) {
      float a0 = 0.f, a1 = 0.f;
      const half8* hp0 = reinterpret_cast<const half8*>(&hcH[0][khq * 264]);
      const half8* hp1 = reinterpret_cast<const half8*>(&hcH[1][khq * 264]);
#pragma unroll 8
      for (int c = 0; c < 32; ++c) {
        half8 w = wq2[c * 512];
        a0 = dot8_(w, hp0[c], a0);   // pad: khq=0/1 on disjoint 4-bank groups
        a1 = dot8_(w, hp1[c], a1);
      }
      a0 += __shfl_xor(a0, 1);       // lane-pair combine: q complete
      a1 += __shfl_xor(a1, 1);
      if (khq == 0) {
        int e = tid >> 1;
        int ei = e + ((e >> 7) << 2);  // padded Qs index
        Qs[0][ei] = __expf(2.f * a0);
        Qs[1][ei] = __expf(2.f * a1);
      }
    } else {
      float ac00 = 0.f, ac01 = 0.f, ac10 = 0.f, ac11 = 0.f;  // [jslot][row]
      const half8* hg0 = reinterpret_cast<const half8*>(&hcH[0][0]);
      const half8* hg1 = reinterpret_cast<const half8*>(&hcH[1][0]);
#pragma unroll 4
      for (int c = 0; c < 32; ++c) {
        half8 h0 = hg0[c];   // broadcast
        half8 h1 = hg1[c];
        half8 w0 = wgJ[c * 1024];
        half8 w1v = wgJ[c * 1024 + 512];
        ac00 = dot8_(w0, h0, ac00);  ac01 = dot8_(w0, h1, ac01);
        ac10 = dot8_(w1v, h0, ac10); ac11 = dot8_(w1v, h1, ac11);
      }
      gfull[0][ug] = ac00;
      gfull[1][ug] = ac01;
      gfull[0][ug + 512] = ac10;
      gfull[1][ug + 512] = ac11;
    }
    __syncthreads();  // B1

    // ---- phase B: scores (lane-pair e-split) + fused softmax reduce, all threads ----
    {
      float sacc0 = 0.f, sacc1 = 0.f;
      const float4* q4 = reinterpret_cast<const float4*>(&Qs[gs][ehp * 132]);
      const float4* w4 = reinterpret_cast<const float4*>(&w2l[ehp * 132]);
      // 8 streamed odd local chunks: issue first (latency hides under LDS math)
      half8 s1 = prowP[1 * 256];
      half8 s3 = prowP[3 * 256];
      half8 s5 = prowP[5 * 256];
      half8 s7 = prowP[7 * 256];
      half8 s9 = prowP[9 * 256];
      half8 s11 = prowP[11 * 256];
      half8 s13 = prowP[13 * 256];
      half8 s15 = prowP[15 * 256];
      // 8 staged even local chunks from LDS (padded region: disjoint banks per pair)
      { half8 l = phlRP[0 * 256]; SC1(l, 0) }
      { half8 l = phlRP[1 * 256]; SC1(l, 2) }
      { half8 l = phlRP[2 * 256]; SC1(l, 4) }
      { half8 l = phlRP[3 * 256]; SC1(l, 6) }
      { half8 l = phlRP[4 * 256]; SC1(l, 8) }
      { half8 l = phlRP[5 * 256]; SC1(l, 10) }
      { half8 l = phlRP[6 * 256]; SC1(l, 12) }
      { half8 l = phlRP[7 * 256]; SC1(l, 14) }
      // streamed odd local chunks
      SC1(s1, 1)  SC1(s3, 3)  SC1(s5, 5)  SC1(s7, 7)
      SC1(s9, 9)  SC1(s11, 11) SC1(s13, 13) SC1(s15, 15)
      float sacc = sacc0 + sacc1;
      sacc += __shfl_xor(sacc, 1);   // lane-pair e-combine: full-e sum
      float ea = __expf(w2sum - 2.f * sacc);  // no max-sub: |sc| <= ~21, fp32-safe
      if (ehp == 0) ealpha[gs][tp] = ea;
      float es = (ehp == 0) ? ea : 0.f;       // avoid double-count in t-reduce
      float ef = es * xfL[gs][tp];
#pragma unroll
      for (int off = 32; off > 0; off >>= 1) {
        es += __shfl_xor(es, off);
        ef += __shfl_xor(ef, off);
      }
      if (lane == 0) { redA[wv] = es; redB[wv] = ef; }  // wv 0..7: row0, 8..15: row1
    }
    __syncthreads();  // B2

    // ---- phase D: LSTM pointwise (tid < 512) ----
    if (tid < 512) {
      const int rb = gp * 8;
      float es = redA[rb + 0] + redA[rb + 1] + redA[rb + 2] + redA[rb + 3] +
                 redA[rb + 4] + redA[rb + 5] + redA[rb + 6] + redA[rb + 7];
      float ef = redB[rb + 0] + redB[rb + 1] + redB[rb + 2] + redB[rb + 3] +
                 redB[rb + 4] + redB[rb + 5] + redB[rb + 6] + redB[rb + 7];
      float yt = ef * rcpf_(es) + fmaf(yhL[gp][s], fcwy, fcb0);
      float gi = fmaf(yt, Wihl[lo], bl[lo]) + gfull[gp][lo];
      float gf = fmaf(yt, Wihl[256 + lo], bl[256 + lo]) + gfull[gp][256 + lo];
      float gc = fmaf(yt, Wihl[512 + lo], bl[512 + lo]) + gfull[gp][512 + lo];
      float go = fmaf(yt, Wihl[768 + lo], bl[768 + lo]) + gfull[gp][768 + lo];
      float iv = sigmoidf_(gi), fv = sigmoidf_(gf), gv = tanhf_(gc), ov = sigmoidf_(go);
      float cold = hc[gp][256 + lo];
      float cn = fmaf(fv, cold, iv * gv);
      float hn = ov * tanhf_(cn);
      hc[gp][lo] = hn;
      hc[gp][256 + lo] = cn;
      hcH[gp][lo] = (_Float16)hn;
      hcH[gp][264 + lo] = (_Float16)cn;
    }
    __syncthreads();  // B3
  }

  // ---- epilogue: context from step-255 ealpha, then out = [h|ctx].fcf ----
  // read last-step softmax sums BEFORE redA/redB get reused
  const float rsA = rcpf_(redA[0] + redA[1] + redA[2] + redA[3] +
                          redA[4] + redA[5] + redA[6] + redA[7]);
  const float rsB = rcpf_(redA[8] + redA[9] + redA[10] + redA[11] +
                          redA[12] + redA[13] + redA[14] + redA[15]);

  float* cpartF = reinterpret_cast<float*>(&PhL[0][0][0]);  // 32KB alias in staged region
  {
    const int gc = tid >> 9, t16 = (tid >> 5) & 15, l5 = tid & 31;
    const half8* xrow = reinterpret_cast<const half8*>(xh) +
                        ((size_t)(b0 + gc) * 256 + t16 * 16) * 32 + l5;
    float acx[8];
#pragma unroll
    for (int m = 0; m < 8; ++m) acx[m] = 0.f;
#pragma unroll 4
    for (int it = 0; it < 16; ++it) {
      float al = ealpha[gc][t16 * 16 + it];
      half8 xv = xrow[it * 32];
#pragma unroll
      for (int m = 0; m < 8; ++m) acx[m] = fmaf(al, (float)xv[m], acx[m]);
    }
    float* dst = &cpartF[((gc * 16 + t16) * 256) + l5 * 8];
    *reinterpret_cast<float4*>(dst) = *reinterpret_cast<float4*>(&acx[0]);
    *reinterpret_cast<float4*>(dst + 4) = *reinterpret_cast<float4*>(&acx[4]);
  }
  __syncthreads();

  if (tid < 512) {
    float cv = 0.f;
#pragma unroll
    for (int u = 0; u < 16; ++u) cv += cpartF[((gp * 16 + u) * 256) + lo];
    cv *= (gp == 0) ? rsA : rsB;
    float hval = hc[gp][lo];
    float p0 = hval * fcfw[lo] + cv * fcfw[256 + lo];
    float p1 = hval * fcfw[512 + lo] + cv * fcfw[768 + lo];
#pragma unroll
    for (int off = 32; off > 0; off >>= 1) {
      p0 += __shfl_xor(p0, off);
      p1 += __shfl_xor(p1, off);
    }
    if (lane == 0) { redA[wv] = p0; redB[wv] = p1; }
  }
  __syncthreads();
  if (tid < 4) {
    int g2 = tid >> 1, o = tid & 1;
    const float* r = (o == 0) ? redA : redB;
    float v = fcfb[o] + r[g2 * 4 + 0] + r[g2 * 4 + 1] + r[g2 * 4 + 2] + r[g2 * 4 + 3];
    out[(b0 + g2) * 2 + o] = v;
  }
}

extern "C" void kernel_launch(void* const* d_in, const int* in_sizes, int n_in,
                              void* d_out, int out_size, void* d_ws, size_t ws_size,
                              hipStream_t stream) {
  (void)in_sizes; (void)n_in; (void)out_size; (void)ws_size;
  const float* x    = (const float*)d_in[0];
  const float* yh   = (const float*)d_in[1];
  const float* w1   = (const float*)d_in[2];
  const float* b1   = (const float*)d_in[3];
  const float* w2   = (const float*)d_in[4];
  /* d_in[5] attn_b2: softmax-invariant, unused */
  const float* Wih  = (const float*)d_in[6];
  const float* Whh  = (const float*)d_in[7];
  const float* bih  = (const float*)d_in[8];
  const float* bhh  = (const float*)d_in[9];
  const float* fcw  = (const float*)d_in[10];
  const float* fcb  = (const float*)d_in[11];
  const float* fcfw = (const float*)d_in[12];
  const float* fcfb = (const float*)d_in[13];
  float* out = (float*)d_out;

  char* ws = (char*)d_ws;
  _Float16* Ph2   = (_Float16*)(ws);                      // 67108864 B
  _Float16* xh    = (_Float16*)(ws + (size_t)67108864);   // 67108864 B
  float*    wT    = (float*)   (ws + (size_t)134217728);  // 262144 B
  _Float16* w1hcQ = (_Float16*)(ws + (size_t)134479872);  // 262144 B
  _Float16* whhG  = (_Float16*)(ws + (size_t)134742016);  // 524288 B
  float*    xf    = (float*)   (ws + (size_t)135266304);  // 524288 B
  // total: 135790592 B (~129.5 MB)

  k_prep_wT   <<<256,   256, 0, stream>>>(w1, wT);
  k_prep_xh   <<<32768, 256, 0, stream>>>(x, xh);
  k_prep_w1hcQ<<<512,   256, 0, stream>>>(w1, w1hcQ);
  k_prep_whhG <<<1024,  256, 0, stream>>>(Whh, whhG);
  k_xf        <<<8192,  256, 0, stream>>>(x, fcw, xf);
  k_encp      <<<8192,  256, 0, stream>>>(x, wT, b1, Ph2);
  k_scan      <<<256,  1024, 0, stream>>>(Ph2, xh, w1hcQ, whhG, xf, yh, w2, Wih,
                                          bih, bhh, fcw, fcb, fcfw, fcfb, out);
}